// Round 9
// baseline (987.553 us; speedup 1.0000x reference)
//
#include <hip/hip_runtime.h>

#define BD 4
#define TD 2048
#define DD 2048
#define DID 4096
#define MD (BD*TD)   // 8192 rows
#define CHK 32       // scan chunks
#define CHL (TD/CHK) // 64 steps/chunk

typedef float f32x4 __attribute__((ext_vector_type(4)));
typedef short s16x8 __attribute__((ext_vector_type(8)));
typedef unsigned short u16;
typedef unsigned short u16x4 __attribute__((ext_vector_type(4)));
typedef unsigned short u16x8 __attribute__((ext_vector_type(8)));

__device__ __forceinline__ float bf2f(u16 u) {
    union { unsigned int i; float f; } v; v.i = ((unsigned int)u) << 16; return v.f;
}
__device__ __forceinline__ u16 f2bf(float f) {
    union { float f; unsigned int i; } v; v.f = f;
    unsigned int r = v.i + 0x7fffu + ((v.i >> 16) & 1u);   // RNE
    return (u16)(r >> 16);
}
__device__ __forceinline__ float sigm(float x) { return 1.f / (1.f + __expf(-x)); }

// Non-volatile register-only MFMA: memory ordering comes from __syncthreads();
// register dataflow (acc chain, af/bq WAR) orders it vs ds_reads. Compiler may
// interleave with reads under its own counted lgkmcnt (m97 mechanism).
__device__ __forceinline__ void mfma16(f32x4& acc, s16x8 a, s16x8 b) {
    asm("v_mfma_f32_16x16x32_bf16 %0, %1, %2, %0" : "+v"(acc) : "v"(a), "v"(b));
}

__device__ __forceinline__ void gload16(const u16* g, u16* l) {
    __builtin_amdgcn_global_load_lds((__attribute__((address_space(1))) void*)(g),
                                     (__attribute__((address_space(3))) void*)(l),
                                     16, 0, 0);
}

// ---------------- fused fp32 -> bf16 weight convert ----------------
// dst layout (u16, contiguous in ws):
//   [W_r; W_i; W_in; W_out]           4 x D*D      (linear)
//   [W_gate/W_up row-interleaved]     2 x DI*D     (per 128-row block: 64 gate + 64 up)
//   [W_down]                          D*DI         (linear)
__global__ __launch_bounds__(256)
void cvt_all(const float4* __restrict__ s0, const float4* __restrict__ s1,
             const float4* __restrict__ s2, const float4* __restrict__ s3,
             const float4* __restrict__ s4, const float4* __restrict__ s5,
             const float4* __restrict__ s6, u16x4* __restrict__ dst, int n4) {
    const int SEG  = DD * DD / 4;   // 1048576 float4
    const int ROWQ = DD / 4;        // 512 float4 per row
    int i = blockIdx.x * blockDim.x + threadIdx.x;
    int stride = gridDim.x * blockDim.x;
    for (; i < n4; i += stride) {
        const float4* s; int off; size_t di;
        if (i < 4 * SEG) {
            int k = i / SEG;
            s = (k == 0) ? s0 : (k == 1) ? s1 : (k == 2) ? s2 : s3;
            off = i - k * SEG;
            di = i;
        } else {
            int j = i - 4 * SEG;
            if (j < 4 * SEG) {                    // gate/up -> interleaved
                int which = j / (2 * SEG);        // 0 gate, 1 up
                int jj = j - which * 2 * SEG;
                int g = jj / ROWQ, cq = jj - g * ROWQ;
                int dr = ((g >> 6) << 7) + (which << 6) + (g & 63);
                s = which ? s5 : s4; off = jj;
                di = (size_t)4 * SEG + (size_t)dr * ROWQ + cq;
            } else {                              // W_down linear
                s = s6; off = j - 4 * SEG;
                di = i;
            }
        }
        float4 v = s[off];
        u16x4 o = { f2bf(v.x), f2bf(v.y), f2bf(v.z), f2bf(v.w) };
        dst[di] = o;
    }
}

// ---------------- RMSNorm: fp32 in -> bf16 out ----------------
__global__ __launch_bounds__(256) void rmsnorm_kernel(const float* __restrict__ x,
                                                      const float* __restrict__ w,
                                                      u16* __restrict__ out) {
    const int row = blockIdx.x;
    const int tid = threadIdx.x;
    const float4* x4 = (const float4*)(x + (size_t)row * DD);
    float4 a = x4[tid * 2], b = x4[tid * 2 + 1];
    float s = a.x*a.x + a.y*a.y + a.z*a.z + a.w*a.w
            + b.x*b.x + b.y*b.y + b.z*b.z + b.w*b.w;
#pragma unroll
    for (int off = 32; off >= 1; off >>= 1) s += __shfl_xor(s, off, 64);
    __shared__ float red[4];
    if ((tid & 63) == 0) red[tid >> 6] = s;
    __syncthreads();
    float tot = red[0] + red[1] + red[2] + red[3];
    float rs = rsqrtf(tot * (1.f / DD) + 1e-6f);
    const float4* w4 = (const float4*)w;
    float4 wa = w4[tid * 2], wb = w4[tid * 2 + 1];
    u16x8 o = { f2bf(a.x*rs*wa.x), f2bf(a.y*rs*wa.y), f2bf(a.z*rs*wa.z), f2bf(a.w*rs*wa.w),
                f2bf(b.x*rs*wb.x), f2bf(b.y*rs*wb.y), f2bf(b.z*rs*wb.z), f2bf(b.w*rs*wb.w) };
    *(u16x8*)(out + (size_t)row * DD + tid * 8) = o;
}

// ========= 128x128 tile GEMM, BK=64, 2-phase double-buffer, C = A*B^T =========
// 4 waves (2x2 of 64x64). LDS: 2 buffers x (A 16KB + B 16KB) = 64 KB. Per
// K-tile: issue next tile's 8 gloads into the OTHER (statically distinct)
// buffer, then reads+MFMA on current, then ONE __syncthreads (the drain waits
// only the remainder of load latency after ~400 cyc of compute cover). x2
// unrolled so buffer index is compile-time (exact alias disambiguation).
// LDS rows XOR-swizzled via pre-swizzled gload SOURCE; reads apply same XOR.
// EPI 0: split-N {r=sigmoid(+b_r), g=sigmoid(+b_i), xp}   EPI 1: outf=resid+c
// EPI 3: fused GLU (B = row-interleaved [gate;up] 64/64 per 128-block):
//        up-waves dump acc to LDS, gate-waves emit silu(g)*u bf16 (64 cols/block)
template<int EPI>
__global__ __launch_bounds__(256)
void gemm_bt(const u16* __restrict__ A, const u16* __restrict__ Bw,
             int M, int N, int K,
             const float* __restrict__ bias0, const float* __restrict__ bias1,
             const float* resid, float* outf,
             u16* __restrict__ out0, u16* __restrict__ out1, u16* __restrict__ out2,
             int Dsub) {
    __shared__ __align__(16) u16 sl[2][2][128 * 64];   // [buf][A/B][..] 64 KB
    const int tid  = threadIdx.x;
    const int lane = tid & 63;
    const int wave = tid >> 6;
    const int wr = (wave >> 1) << 6;
    const int wc = (wave & 1) << 6;
    const int brow = blockIdx.x * 128;
    const int bcol = blockIdx.y * 128;

    // staging: 32 rows/issue, 8 chunks/row; source chunk pre-swizzled
    const int srow  = tid >> 3;                    // 0..31
    const int schnk = (tid & 7) ^ (srow & 7);      // inverse-swizzle source
    const size_t soff = (size_t)srow * K + (schnk << 3);
    const u16* gA = A  + (size_t)brow * K + soff;
    const u16* gB = Bw + (size_t)bcol * K + soff;

    // read-address pieces
    const int fr = lane & 15;
    const int lg = lane >> 4;                      // 0..3
    const int ck0 = ((lg)     ^ (fr & 7)) << 4;    // k-half 0 chunk byte
    const int ck1 = ((4 + lg) ^ (fr & 7)) << 4;    // k-half 1 chunk byte

    f32x4 acc[4][4];
#pragma unroll
    for (int i = 0; i < 4; ++i)
#pragma unroll
        for (int j = 0; j < 4; ++j)
            acc[i][j] = (f32x4){0.f, 0.f, 0.f, 0.f};

    const int Tn = K >> 6;

#define STAGE_TILE(BUF, TS) do {                                            \
        const size_t ko_ = (size_t)(TS) << 6;                               \
        _Pragma("unroll")                                                   \
        for (int s = 0; s < 4; ++s) {                                       \
            gload16(gA + ko_ + (size_t)s * 32 * K, &sl[BUF][0][tid*8 + s*2048]); \
            gload16(gB + ko_ + (size_t)s * 32 * K, &sl[BUF][1][tid*8 + s*2048]); \
        }                                                                   \
    } while (0)

#define COMPUTE_TILE(BUF) do {                                              \
        const char* lAc_ = (const char*)&sl[BUF][0][0];                     \
        const char* lBc_ = (const char*)&sl[BUF][1][0];                     \
        s16x8 af[4][2], bq[4][2];                                           \
        _Pragma("unroll")                                                   \
        for (int i = 0; i < 4; ++i) {                                       \
            const int ra = (wr + i * 16 + fr) * 128;                        \
            const int rb = (wc + i * 16 + fr) * 128;                        \
            af[i][0] = *(const s16x8*)(lAc_ + ra + ck0);                    \
            af[i][1] = *(const s16x8*)(lAc_ + ra + ck1);                    \
            bq[i][0] = *(const s16x8*)(lBc_ + rb + ck0);                    \
            bq[i][1] = *(const s16x8*)(lBc_ + rb + ck1);                    \
        }                                                                   \
        _Pragma("unroll")                                                   \
        for (int h = 0; h < 2; ++h)                                         \
            _Pragma("unroll")                                               \
            for (int i = 0; i < 4; ++i)                                     \
                _Pragma("unroll")                                           \
                for (int j = 0; j < 4; ++j)                                 \
                    mfma16(acc[i][j], af[i][h], bq[j][h]);                  \
    } while (0)

    // prologue: stage tile 0 into buf0; drain; barrier
    STAGE_TILE(0, 0);
    __syncthreads();

    for (int t = 0; t < Tn; t += 2) {
        // tile t: stage t+1 -> buf1 FIRST, compute on buf0, one barrier
        STAGE_TILE(1, t + 1 < Tn ? t + 1 : t);
        COMPUTE_TILE(0);
        __syncthreads();
        // tile t+1: stage t+2 -> buf0, compute on buf1, one barrier
        STAGE_TILE(0, t + 2 < Tn ? t + 2 : t + 1);
        COMPUTE_TILE(1);
        __syncthreads();
    }

#undef STAGE_TILE
#undef COMPUTE_TILE

    // MFMA-write -> VALU-read hazard fence
#pragma unroll
    for (int i = 0; i < 4; ++i)
#pragma unroll
        for (int j = 0; j < 4; ++j)
            asm volatile("s_nop 7" : "+v"(acc[i][j]));

    if (EPI == 3) {
        // fused GLU: up-waves (wc==64) stash acc in LDS; gate-waves multiply.
        float* up_lds = (float*)&sl[0][0][0];    // 128 x 65 fp32 = 33.3 KB
        if (wc) {
#pragma unroll
            for (int i = 0; i < 4; ++i)
#pragma unroll
                for (int j = 0; j < 4; ++j)
#pragma unroll
                    for (int e = 0; e < 4; ++e) {
                        const int row = wr + i * 16 + (lg << 2) + e;
                        const int col = fr + j * 16;
                        up_lds[row * 65 + col] = acc[i][j][e];
                    }
        }
        __syncthreads();
        if (!wc) {
            const int gc0 = bcol >> 1;
#pragma unroll
            for (int i = 0; i < 4; ++i)
#pragma unroll
                for (int j = 0; j < 4; ++j)
#pragma unroll
                    for (int e = 0; e < 4; ++e) {
                        const int row = wr + i * 16 + (lg << 2) + e;
                        const int col = fr + j * 16;
                        const float u = up_lds[row * 65 + col];
                        const float g = acc[i][j][e];
                        out0[(size_t)(brow + row) * Dsub + gc0 + col] = f2bf(g * sigm(g) * u);
                    }
        }
        return;
    }

    const int r0 = brow + wr + (lg << 2);
    const int c0 = bcol + wc + fr;
#pragma unroll
    for (int i = 0; i < 4; ++i) {
#pragma unroll
        for (int j = 0; j < 4; ++j) {
            const int gcol = c0 + j * 16;
#pragma unroll
            for (int e = 0; e < 4; ++e) {
                const int grow = r0 + i * 16 + e;
                float c = acc[i][j][e];
                if (EPI == 0) {
                    if (gcol < Dsub) {
                        out0[(size_t)grow * Dsub + gcol] = f2bf(sigm(c + bias0[gcol]));
                    } else if (gcol < 2 * Dsub) {
                        out1[(size_t)grow * Dsub + (gcol - Dsub)] = f2bf(sigm(c + bias1[gcol - Dsub]));
                    } else {
                        out2[(size_t)grow * Dsub + (gcol - 2 * Dsub)] = f2bf(c);
                    }
                } else if (EPI == 1) {
                    const size_t idx = (size_t)grow * N + gcol;
                    outf[idx] = resid[idx] + c;
                }
            }
        }
    }
}

// ================= chunked RG-LRU scan (3 passes) =================
__global__ __launch_bounds__(256)
void scan_partial(const u16* __restrict__ R, const u16* __restrict__ XP,
                  const float* __restrict__ log_dec, float* __restrict__ carry) {
    const int d = blockIdx.x * 256 + threadIdx.x;
    const int k = blockIdx.y;
    const int b = blockIdx.z;
    float a = sigm(log_dec[d]);
    a = fminf(fmaxf(a, 1e-6f), 1.f - 1e-6f);
    const float sc = sqrtf(fmaxf(1.f - a * a, 0.f));
    float h = 0.f;
    size_t idx = ((size_t)b * TD + (size_t)k * CHL) * DD + d;
#pragma unroll 8
    for (int t = 0; t < CHL; ++t) {
        h = a * h + sc * (bf2f(R[idx]) * bf2f(XP[idx]));
        idx += DD;
    }
    carry[((size_t)b * CHK + k) * DD + d] = h;
}

__global__ __launch_bounds__(256)
void scan_carry(const float* __restrict__ state, const float* __restrict__ log_dec,
                const float* __restrict__ carry, float* __restrict__ carryin,
                float* __restrict__ hfin) {
    const int d = blockIdx.x * 256 + threadIdx.x;
    const int b = blockIdx.y;
    float a = sigm(log_dec[d]);
    a = fminf(fmaxf(a, 1e-6f), 1.f - 1e-6f);
    float aL = a;
#pragma unroll
    for (int i = 0; i < 6; ++i) aL *= aL;   // a^64 == a^CHL
    float h = state[(size_t)b * DD + d];
#pragma unroll
    for (int k = 0; k < CHK; ++k) {
        const size_t ci = ((size_t)b * CHK + k) * DD + d;
        carryin[ci] = h;
        h = aL * h + carry[ci];
    }
    hfin[(size_t)b * DD + d] = h;
}

__global__ __launch_bounds__(256)
void scan_final(const u16* __restrict__ R, const u16* __restrict__ XP,
                const u16* __restrict__ G, const float* __restrict__ log_dec,
                const float* __restrict__ carryin, u16* __restrict__ HSG) {
    const int d = blockIdx.x * 256 + threadIdx.x;
    const int k = blockIdx.y;
    const int b = blockIdx.z;
    float a = sigm(log_dec[d]);
    a = fminf(fmaxf(a, 1e-6f), 1.f - 1e-6f);
    const float sc = sqrtf(fmaxf(1.f - a * a, 0.f));
    float h = carryin[((size_t)b * CHK + k) * DD + d];
    size_t idx = ((size_t)b * TD + (size_t)k * CHL) * DD + d;
#pragma unroll 8
    for (int t = 0; t < CHL; ++t) {
        h = a * h + sc * (bf2f(R[idx]) * bf2f(XP[idx]));
        HSG[idx] = f2bf(h * bf2f(G[idx]));
        idx += DD;
    }
}

extern "C" void kernel_launch(void* const* d_in, const int* in_sizes, int n_in,
                              void* d_out, int out_size, void* d_ws, size_t ws_size,
                              hipStream_t stream) {
    const float* x       = (const float*)d_in[0];
    const float* state   = (const float*)d_in[1];
    const float* w_norm1 = (const float*)d_in[2];
    const float* W_in    = (const float*)d_in[3];
    const float* W_r     = (const float*)d_in[4];
    const float* b_r     = (const float*)d_in[5];
    const float* W_i     = (const float*)d_in[6];
    const float* b_i     = (const float*)d_in[7];
    const float* log_dec = (const float*)d_in[8];
    const float* W_out   = (const float*)d_in[9];
    const float* w_norm2 = (const float*)d_in[10];
    const float* W_gate  = (const float*)d_in[11];
    const float* W_up    = (const float*)d_in[12];
    const float* W_down  = (const float*)d_in[13];

    float* out  = (float*)d_out;
    float* hfin = out + (size_t)MD * DD;

    u16* wstack1 = (u16*)d_ws;                              // [W_r;W_i;W_in] 3*D*D
    u16* wout2   = wstack1 + (size_t)3 * DD * DD;           // W_out D*D
    u16* wstack2 = wout2   + (size_t)DD * DD;               // [gate/up interleaved] 2*DI*D
    u16* wdown2  = wstack2 + (size_t)2 * DID * DD;          // W_down D*DI
    u16* bufN    = wdown2  + (size_t)DD * DID;              // M*D
    u16* bufR    = bufN    + (size_t)MD * DD;               // M*D  (later: act M*DI spans bufR+bufG)
    u16* bufG    = bufR    + (size_t)MD * DD;               // M*D
    u16* bufXP   = bufG    + (size_t)MD * DD;               // M*D
    u16* spare   = bufXP   + (size_t)MD * DD;               // M*D spare
    float* carry   = (float*)spare;                         // B*CHK*D fp32 (1 MB)
    float* carryin = carry + (size_t)BD * CHK * DD;         // B*CHK*D fp32 (1 MB)

    // 1) fused weight converts (gate/up interleaved for the fused-GLU GEMM)
    cvt_all<<<2048, 256, 0, stream>>>((const float4*)W_r, (const float4*)W_i,
                                      (const float4*)W_in, (const float4*)W_out,
                                      (const float4*)W_gate, (const float4*)W_up,
                                      (const float4*)W_down, (u16x4*)wstack1,
                                      (3*DD*DD + DD*DD + 2*DID*DD + DD*DID) / 4);

    rmsnorm_kernel<<<MD, 256, 0, stream>>>(x, w_norm1, bufN);

    // r/g/xp projections: M=8192, N=6144, K=2048
    {
        dim3 g1(MD / 128, (3 * DD) / 128);
        gemm_bt<0><<<g1, 256, 0, stream>>>(bufN, wstack1, MD, 3 * DD, DD,
                                           b_r, b_i, nullptr, nullptr, bufR, bufG, bufXP, DD);
    }

    // chunked RG-LRU scan
    {
        dim3 gp(DD / 256, CHK, BD);
        scan_partial<<<gp, 256, 0, stream>>>(bufR, bufXP, log_dec, carry);
        dim3 gc(DD / 256, BD);
        scan_carry<<<gc, 256, 0, stream>>>(state, log_dec, carry, carryin, hfin);
        scan_final<<<gp, 256, 0, stream>>>(bufR, bufXP, bufG, log_dec, carryin, bufN);
    }

    // x2 = x + hsg @ W_out^T
    {
        dim3 g2(MD / 128, DD / 128);
        gemm_bt<1><<<g2, 256, 0, stream>>>(bufN, wout2, MD, DD, DD,
                                           nullptr, nullptr, x, out, nullptr, nullptr, nullptr, 0);
    }

    rmsnorm_kernel<<<MD, 256, 0, stream>>>(out, w_norm2, bufN);

    // fused gate/up + GLU: stacked N=8192, writes act (M x DI) directly
    {
        dim3 g3(MD / 128, (2 * DID) / 128);
        gemm_bt<3><<<g3, 256, 0, stream>>>(bufN, wstack2, MD, 2 * DID, DD,
                                           nullptr, nullptr, nullptr, nullptr, bufR, nullptr, nullptr, DID);
    }

    // out = x2 + act @ W_down^T
    {
        dim3 g4(MD / 128, DD / 128);
        gemm_bt<1><<<g4, 256, 0, stream>>>(bufR, wdown2, MD, DD, DID,
                                           nullptr, nullptr, out, out, nullptr, nullptr, nullptr, 0);
    }
}

// Round 10
// 858.101 us; speedup vs baseline: 1.1509x; 1.1509x over previous
//
#include <hip/hip_runtime.h>

#define BD 4
#define TD 2048
#define DD 2048
#define DID 4096
#define MD (BD*TD)   // 8192 rows
#define CHK 32       // scan chunks
#define CHL (TD/CHK) // 64 steps/chunk

typedef float f32x4 __attribute__((ext_vector_type(4)));
typedef short s16x8 __attribute__((ext_vector_type(8)));
typedef unsigned short u16;
typedef unsigned short u16x4 __attribute__((ext_vector_type(4)));
typedef unsigned short u16x8 __attribute__((ext_vector_type(8)));

__device__ __forceinline__ float bf2f(u16 u) {
    union { unsigned int i; float f; } v; v.i = ((unsigned int)u) << 16; return v.f;
}
__device__ __forceinline__ u16 f2bf(float f) {
    union { float f; unsigned int i; } v; v.f = f;
    unsigned int r = v.i + 0x7fffu + ((v.i >> 16) & 1u);   // RNE
    return (u16)(r >> 16);
}
__device__ __forceinline__ float sigm(float x) { return 1.f / (1.f + __expf(-x)); }

// Non-volatile register-only MFMA: memory ordering comes from __syncthreads();
// register dataflow orders it vs ds_reads (m97 mechanism).
__device__ __forceinline__ void mfma16(f32x4& acc, s16x8 a, s16x8 b) {
    asm("v_mfma_f32_16x16x32_bf16 %0, %1, %2, %0" : "+v"(acc) : "v"(a), "v"(b));
}

__device__ __forceinline__ void gload16(const u16* g, u16* l) {
    __builtin_amdgcn_global_load_lds((__attribute__((address_space(1))) void*)(g),
                                     (__attribute__((address_space(3))) void*)(l),
                                     16, 0, 0);
}

// ---------------- fused fp32 -> bf16 weight convert ----------------
// dst layout (u16, contiguous in ws):
//   [W_r; W_i; W_in; W_out]   4 x D*D (linear)
//   [gate/up 32-row interleave] 2 x DI*D : per 128-row block nb:
//       r 0-31 = gate[nb*64 .. +32), r 32-63 = up[nb*64 .. +32),
//       r 64-95 = gate[nb*64+32 ..), r 96-127 = up[nb*64+32 ..)
//   [W_down] D*DI (linear)
__global__ __launch_bounds__(256)
void cvt_all(const float4* __restrict__ s0, const float4* __restrict__ s1,
             const float4* __restrict__ s2, const float4* __restrict__ s3,
             const float4* __restrict__ s4, const float4* __restrict__ s5,
             const float4* __restrict__ s6, u16x4* __restrict__ dst, int n4) {
    const int SEG  = DD * DD / 4;   // 1048576 float4
    const int ROWQ = DD / 4;        // 512 float4 per row
    int i = blockIdx.x * blockDim.x + threadIdx.x;
    int stride = gridDim.x * blockDim.x;
    for (; i < n4; i += stride) {
        const float4* s; int off; size_t di;
        if (i < 4 * SEG) {
            int k = i / SEG;
            s = (k == 0) ? s0 : (k == 1) ? s1 : (k == 2) ? s2 : s3;
            off = i - k * SEG;
            di = i;
        } else {
            int j = i - 4 * SEG;
            if (j < 4 * SEG) {                    // gate/up -> 32-row interleave
                int which = j / (2 * SEG);        // 0 gate, 1 up
                int jj = j - which * 2 * SEG;
                int g = jj / ROWQ, cq = jj - g * ROWQ;
                int nb = g >> 6, ii = g & 63;
                int dr;
                if (which == 0) dr = nb * 128 + (ii < 32 ? ii : ii + 32);
                else            dr = nb * 128 + (ii < 32 ? ii + 32 : ii + 64);
                s = which ? s5 : s4; off = jj;
                di = (size_t)4 * SEG + (size_t)dr * ROWQ + cq;
            } else {                              // W_down linear
                s = s6; off = j - 4 * SEG;
                di = i;
            }
        }
        float4 v = s[off];
        u16x4 o = { f2bf(v.x), f2bf(v.y), f2bf(v.z), f2bf(v.w) };
        dst[di] = o;
    }
}

// ---------------- RMSNorm: fp32 in -> bf16 out ----------------
__global__ __launch_bounds__(256) void rmsnorm_kernel(const float* __restrict__ x,
                                                      const float* __restrict__ w,
                                                      u16* __restrict__ out) {
    const int row = blockIdx.x;
    const int tid = threadIdx.x;
    const float4* x4 = (const float4*)(x + (size_t)row * DD);
    float4 a = x4[tid * 2], b = x4[tid * 2 + 1];
    float s = a.x*a.x + a.y*a.y + a.z*a.z + a.w*a.w
            + b.x*b.x + b.y*b.y + b.z*b.z + b.w*b.w;
#pragma unroll
    for (int off = 32; off >= 1; off >>= 1) s += __shfl_xor(s, off, 64);
    __shared__ float red[4];
    if ((tid & 63) == 0) red[tid >> 6] = s;
    __syncthreads();
    float tot = red[0] + red[1] + red[2] + red[3];
    float rs = rsqrtf(tot * (1.f / DD) + 1e-6f);
    const float4* w4 = (const float4*)w;
    float4 wa = w4[tid * 2], wb = w4[tid * 2 + 1];
    u16x8 o = { f2bf(a.x*rs*wa.x), f2bf(a.y*rs*wa.y), f2bf(a.z*rs*wa.z), f2bf(a.w*rs*wa.w),
                f2bf(b.x*rs*wb.x), f2bf(b.y*rs*wb.y), f2bf(b.z*rs*wb.z), f2bf(b.w*rs*wb.w) };
    *(u16x8*)(out + (size_t)row * DD + tid * 8) = o;
}

// ============ 128x128 tile GEMM, BK=64, C = A(MxK) * B(NxK)^T ============
// Round-8 proven structure: 4 waves (2x2 of 64x64), single-buffered 32 KB LDS,
// __syncthreads ordering, XOR-swizzled rows via pre-swizzled gload SOURCE.
// EPI 0: split-N {r=sigmoid(+b_r), g=sigmoid(+b_i), xp}  EPI 1: outf=resid+c
// EPI 3: fused GLU, zero-cost: B is 32-row gate/up interleaved, so the up
//        value for gate acc[i][j] (j in {0,1}) is acc[i][j+2] in the SAME
//        thread -> silu(g)*u computed locally; 64 act cols written per block.
template<int EPI>
__global__ __launch_bounds__(256)
void gemm_bt(const u16* __restrict__ A, const u16* __restrict__ Bw,
             int M, int N, int K,
             const float* __restrict__ bias0, const float* __restrict__ bias1,
             const float* resid, float* outf,
             u16* __restrict__ out0, u16* __restrict__ out1, u16* __restrict__ out2,
             int Dsub) {
    __shared__ __align__(16) u16 lA[128 * 64];   // 16 KB
    __shared__ __align__(16) u16 lB[128 * 64];   // 16 KB
    const int tid  = threadIdx.x;
    const int lane = tid & 63;
    const int wave = tid >> 6;
    const int wr = (wave >> 1) << 6;
    const int wc = (wave & 1) << 6;
    const int brow = blockIdx.x * 128;
    const int bcol = blockIdx.y * 128;

    // staging: 32 rows/issue, 8 chunks/row; source chunk pre-swizzled
    const int srow  = tid >> 3;                    // 0..31
    const int schnk = (tid & 7) ^ (srow & 7);      // inverse-swizzle source
    const size_t soff = (size_t)srow * K + (schnk << 3);
    const u16* gA = A  + (size_t)brow * K + soff;
    const u16* gB = Bw + (size_t)bcol * K + soff;
    u16* lAp = lA + tid * 8;                       // linear dest, lane*16B
    u16* lBp = lB + tid * 8;

    // read-address pieces
    const int fr = lane & 15;
    const int lg = lane >> 4;                      // 0..3
    const int ck0 = ((lg)     ^ (fr & 7)) << 4;    // k-half 0 chunk byte
    const int ck1 = ((4 + lg) ^ (fr & 7)) << 4;    // k-half 1 chunk byte
    const char* lAc = (const char*)lA;
    const char* lBc = (const char*)lB;

    f32x4 acc[4][4];
#pragma unroll
    for (int i = 0; i < 4; ++i)
#pragma unroll
        for (int j = 0; j < 4; ++j)
            acc[i][j] = (f32x4){0.f, 0.f, 0.f, 0.f};

    for (int k0 = 0; k0 < K; k0 += 64) {
#pragma unroll
        for (int s = 0; s < 4; ++s) {
            gload16(gA + k0 + (size_t)s * 32 * K, lAp + s * 2048);
            gload16(gB + k0 + (size_t)s * 32 * K, lBp + s * 2048);
        }
        __syncthreads();
        s16x8 af[4][2], bq[4][2];
#pragma unroll
        for (int i = 0; i < 4; ++i) {
            const int ra = (wr + i * 16 + fr) * 128;
            const int rb = (wc + i * 16 + fr) * 128;
            af[i][0] = *(const s16x8*)(lAc + ra + ck0);
            af[i][1] = *(const s16x8*)(lAc + ra + ck1);
            bq[i][0] = *(const s16x8*)(lBc + rb + ck0);
            bq[i][1] = *(const s16x8*)(lBc + rb + ck1);
        }
#pragma unroll
        for (int h = 0; h < 2; ++h)
#pragma unroll
            for (int i = 0; i < 4; ++i)
#pragma unroll
                for (int j = 0; j < 4; ++j)
                    mfma16(acc[i][j], af[i][h], bq[j][h]);
        __syncthreads();
    }

    // MFMA-write -> VALU-read hazard fence
#pragma unroll
    for (int i = 0; i < 4; ++i)
#pragma unroll
        for (int j = 0; j < 4; ++j)
            asm volatile("s_nop 7" : "+v"(acc[i][j]));

    if (EPI == 3) {
        // fused GLU: gate acc[i][0..1] pairs with up acc[i][2..3], same thread
        const int nb = bcol >> 7;
        const int cbase = nb * 64 + (wc ? 32 : 0);
        const int r0 = brow + wr + (lg << 2);
#pragma unroll
        for (int i = 0; i < 4; ++i)
#pragma unroll
            for (int j = 0; j < 2; ++j)
#pragma unroll
                for (int e = 0; e < 4; ++e) {
                    const int grow = r0 + i * 16 + e;
                    const float g = acc[i][j][e];
                    const float u = acc[i][j + 2][e];
                    out0[(size_t)grow * Dsub + cbase + j * 16 + fr] = f2bf(g * sigm(g) * u);
                }
        return;
    }

    const int r0 = brow + wr + (lg << 2);
    const int c0 = bcol + wc + fr;
#pragma unroll
    for (int i = 0; i < 4; ++i) {
#pragma unroll
        for (int j = 0; j < 4; ++j) {
            const int gcol = c0 + j * 16;
#pragma unroll
            for (int e = 0; e < 4; ++e) {
                const int grow = r0 + i * 16 + e;
                float c = acc[i][j][e];
                if (EPI == 0) {
                    if (gcol < Dsub) {
                        out0[(size_t)grow * Dsub + gcol] = f2bf(sigm(c + bias0[gcol]));
                    } else if (gcol < 2 * Dsub) {
                        out1[(size_t)grow * Dsub + (gcol - Dsub)] = f2bf(sigm(c + bias1[gcol - Dsub]));
                    } else {
                        out2[(size_t)grow * Dsub + (gcol - 2 * Dsub)] = f2bf(c);
                    }
                } else if (EPI == 1) {
                    const size_t idx = (size_t)grow * N + gcol;
                    outf[idx] = resid[idx] + c;
                }
            }
        }
    }
}

// ================= chunked RG-LRU scan (3 passes) =================
__global__ __launch_bounds__(256)
void scan_partial(const u16* __restrict__ R, const u16* __restrict__ XP,
                  const float* __restrict__ log_dec, float* __restrict__ carry) {
    const int d = blockIdx.x * 256 + threadIdx.x;
    const int k = blockIdx.y;
    const int b = blockIdx.z;
    float a = sigm(log_dec[d]);
    a = fminf(fmaxf(a, 1e-6f), 1.f - 1e-6f);
    const float sc = sqrtf(fmaxf(1.f - a * a, 0.f));
    float h = 0.f;
    size_t idx = ((size_t)b * TD + (size_t)k * CHL) * DD + d;
#pragma unroll 8
    for (int t = 0; t < CHL; ++t) {
        h = a * h + sc * (bf2f(R[idx]) * bf2f(XP[idx]));
        idx += DD;
    }
    carry[((size_t)b * CHK + k) * DD + d] = h;
}

__global__ __launch_bounds__(256)
void scan_carry(const float* __restrict__ state, const float* __restrict__ log_dec,
                const float* __restrict__ carry, float* __restrict__ carryin,
                float* __restrict__ hfin) {
    const int d = blockIdx.x * 256 + threadIdx.x;
    const int b = blockIdx.y;
    float a = sigm(log_dec[d]);
    a = fminf(fmaxf(a, 1e-6f), 1.f - 1e-6f);
    float aL = a;
#pragma unroll
    for (int i = 0; i < 6; ++i) aL *= aL;   // a^64 == a^CHL
    float h = state[(size_t)b * DD + d];
#pragma unroll
    for (int k = 0; k < CHK; ++k) {
        const size_t ci = ((size_t)b * CHK + k) * DD + d;
        carryin[ci] = h;
        h = aL * h + carry[ci];
    }
    hfin[(size_t)b * DD + d] = h;
}

__global__ __launch_bounds__(256)
void scan_final(const u16* __restrict__ R, const u16* __restrict__ XP,
                const u16* __restrict__ G, const float* __restrict__ log_dec,
                const float* __restrict__ carryin, u16* __restrict__ HSG) {
    const int d = blockIdx.x * 256 + threadIdx.x;
    const int k = blockIdx.y;
    const int b = blockIdx.z;
    float a = sigm(log_dec[d]);
    a = fminf(fmaxf(a, 1e-6f), 1.f - 1e-6f);
    const float sc = sqrtf(fmaxf(1.f - a * a, 0.f));
    float h = carryin[((size_t)b * CHK + k) * DD + d];
    size_t idx = ((size_t)b * TD + (size_t)k * CHL) * DD + d;
#pragma unroll 8
    for (int t = 0; t < CHL; ++t) {
        h = a * h + sc * (bf2f(R[idx]) * bf2f(XP[idx]));
        HSG[idx] = f2bf(h * bf2f(G[idx]));
        idx += DD;
    }
}

extern "C" void kernel_launch(void* const* d_in, const int* in_sizes, int n_in,
                              void* d_out, int out_size, void* d_ws, size_t ws_size,
                              hipStream_t stream) {
    const float* x       = (const float*)d_in[0];
    const float* state   = (const float*)d_in[1];
    const float* w_norm1 = (const float*)d_in[2];
    const float* W_in    = (const float*)d_in[3];
    const float* W_r     = (const float*)d_in[4];
    const float* b_r     = (const float*)d_in[5];
    const float* W_i     = (const float*)d_in[6];
    const float* b_i     = (const float*)d_in[7];
    const float* log_dec = (const float*)d_in[8];
    const float* W_out   = (const float*)d_in[9];
    const float* w_norm2 = (const float*)d_in[10];
    const float* W_gate  = (const float*)d_in[11];
    const float* W_up    = (const float*)d_in[12];
    const float* W_down  = (const float*)d_in[13];

    float* out  = (float*)d_out;
    float* hfin = out + (size_t)MD * DD;

    u16* wstack1 = (u16*)d_ws;                              // [W_r;W_i;W_in] 3*D*D
    u16* wout2   = wstack1 + (size_t)3 * DD * DD;           // W_out D*D
    u16* wstack2 = wout2   + (size_t)DD * DD;               // [gate/up interleaved] 2*DI*D
    u16* wdown2  = wstack2 + (size_t)2 * DID * DD;          // W_down D*DI
    u16* bufN    = wdown2  + (size_t)DD * DID;              // M*D
    u16* bufR    = bufN    + (size_t)MD * DD;               // M*D (later: act M*DI spans bufR+bufG)
    u16* bufG    = bufR    + (size_t)MD * DD;               // M*D
    u16* bufXP   = bufG    + (size_t)MD * DD;               // M*D
    u16* spare   = bufXP   + (size_t)MD * DD;               // M*D spare
    float* carry   = (float*)spare;                         // B*CHK*D fp32 (1 MB)
    float* carryin = carry + (size_t)BD * CHK * DD;         // B*CHK*D fp32 (1 MB)

    // 1) fused weight converts (gate/up 32-row interleaved for the fused-GLU GEMM)
    cvt_all<<<2048, 256, 0, stream>>>((const float4*)W_r, (const float4*)W_i,
                                      (const float4*)W_in, (const float4*)W_out,
                                      (const float4*)W_gate, (const float4*)W_up,
                                      (const float4*)W_down, (u16x4*)wstack1,
                                      (3*DD*DD + DD*DD + 2*DID*DD + DD*DID) / 4);

    rmsnorm_kernel<<<MD, 256, 0, stream>>>(x, w_norm1, bufN);

    // r/g/xp projections: M=8192, N=6144, K=2048
    {
        dim3 g1(MD / 128, (3 * DD) / 128);
        gemm_bt<0><<<g1, 256, 0, stream>>>(bufN, wstack1, MD, 3 * DD, DD,
                                           b_r, b_i, nullptr, nullptr, bufR, bufG, bufXP, DD);
    }

    // chunked RG-LRU scan
    {
        dim3 gp(DD / 256, CHK, BD);
        scan_partial<<<gp, 256, 0, stream>>>(bufR, bufXP, log_dec, carry);
        dim3 gc(DD / 256, BD);
        scan_carry<<<gc, 256, 0, stream>>>(state, log_dec, carry, carryin, hfin);
        scan_final<<<gp, 256, 0, stream>>>(bufR, bufXP, bufG, log_dec, carryin, bufN);
    }

    // x2 = x + hsg @ W_out^T
    {
        dim3 g2(MD / 128, DD / 128);
        gemm_bt<1><<<g2, 256, 0, stream>>>(bufN, wout2, MD, DD, DD,
                                           nullptr, nullptr, x, out, nullptr, nullptr, nullptr, 0);
    }

    rmsnorm_kernel<<<MD, 256, 0, stream>>>(out, w_norm2, bufN);

    // fused gate/up + GLU: stacked N=8192, writes act (M x DI) directly
    {
        dim3 g3(MD / 128, (2 * DID) / 128);
        gemm_bt<3><<<g3, 256, 0, stream>>>(bufN, wstack2, MD, 2 * DID, DD,
                                           nullptr, nullptr, nullptr, nullptr, bufR, nullptr, nullptr, DID);
    }

    // out = x2 + act @ W_down^T
    {
        dim3 g4(MD / 128, DD / 128);
        gemm_bt<1><<<g4, 256, 0, stream>>>(bufR, wdown2, MD, DD, DID,
                                           nullptr, nullptr, out, out, nullptr, nullptr, nullptr, 0);
    }
}

// Round 11
// 816.680 us; speedup vs baseline: 1.2092x; 1.0507x over previous
//
#include <hip/hip_runtime.h>

#define BD 4
#define TD 2048
#define DD 2048
#define DID 4096
#define MD (BD*TD)   // 8192 rows
#define CHK 32       // scan chunks
#define CHL (TD/CHK) // 64 steps/chunk

typedef float f32x4 __attribute__((ext_vector_type(4)));
typedef short s16x8 __attribute__((ext_vector_type(8)));
typedef unsigned short u16;
typedef unsigned short u16x4 __attribute__((ext_vector_type(4)));
typedef unsigned short u16x8 __attribute__((ext_vector_type(8)));

__device__ __forceinline__ float bf2f(u16 u) {
    union { unsigned int i; float f; } v; v.i = ((unsigned int)u) << 16; return v.f;
}
__device__ __forceinline__ u16 f2bf(float f) {
    union { float f; unsigned int i; } v; v.f = f;
    unsigned int r = v.i + 0x7fffu + ((v.i >> 16) & 1u);   // RNE
    return (u16)(r >> 16);
}
__device__ __forceinline__ float sigm(float x) { return 1.f / (1.f + __expf(-x)); }

// Non-volatile register-only MFMA: memory ordering comes from __syncthreads();
// register dataflow orders it vs ds_reads (m97 mechanism).
__device__ __forceinline__ void mfma16(f32x4& acc, s16x8 a, s16x8 b) {
    asm("v_mfma_f32_16x16x32_bf16 %0, %1, %2, %0" : "+v"(acc) : "v"(a), "v"(b));
}

__device__ __forceinline__ void gload16(const u16* g, u16* l) {
    __builtin_amdgcn_global_load_lds((__attribute__((address_space(1))) void*)(g),
                                     (__attribute__((address_space(3))) void*)(l),
                                     16, 0, 0);
}

// ---------------- fused fp32 -> bf16 weight convert ----------------
// dst layout (u16, contiguous in ws), SEG = D*D elems:
//   [W_r/W_in 32-row interleave] 2*SEG : per 128-row block nb:
//       r 0-31 = W_r[nb*64..+32), 32-63 = W_in[nb*64..+32),
//       r 64-95 = W_r[+32..64),   96-127 = W_in[+32..64)
//   [W_i]    SEG      at 2*SEG
//   [W_out]  SEG      at 3*SEG
//   [gate/up 32-row interleave] 4*SEG at 4*SEG   (same scheme)
//   [W_down] 2*SEG    at 8*SEG
__global__ __launch_bounds__(256)
void cvt_all(const float4* __restrict__ sr, const float4* __restrict__ sin_,
             const float4* __restrict__ si, const float4* __restrict__ sout,
             const float4* __restrict__ sg, const float4* __restrict__ su,
             const float4* __restrict__ sd, u16x4* __restrict__ dst, int n4) {
    const int SEG  = DD * DD / 4;   // 1048576 float4
    const int ROWQ = DD / 4;        // 512 float4 per row
    int i = blockIdx.x * blockDim.x + threadIdx.x;
    int stride = gridDim.x * blockDim.x;
    for (; i < n4; i += stride) {
        const float4* s; int off; size_t di;
        if (i < 2 * SEG) {                        // W_r / W_in -> interleave
            int which = i / SEG;                  // 0 = W_r, 1 = W_in
            int jj = i - which * SEG;
            int g = jj / ROWQ, cq = jj - g * ROWQ;
            int nb = g >> 6, ii = g & 63;
            int dr = which == 0 ? nb * 128 + (ii < 32 ? ii : ii + 32)
                                : nb * 128 + (ii < 32 ? ii + 32 : ii + 64);
            s = which ? sin_ : sr; off = jj;
            di = (size_t)dr * ROWQ + cq;
        } else if (i < 3 * SEG) {                 // W_i linear
            s = si; off = i - 2 * SEG; di = i;
        } else if (i < 4 * SEG) {                 // W_out linear
            s = sout; off = i - 3 * SEG; di = i;
        } else if (i < 8 * SEG) {                 // gate/up -> interleave
            int j = i - 4 * SEG;
            int which = j / (2 * SEG);            // 0 gate, 1 up
            int jj = j - which * 2 * SEG;
            int g = jj / ROWQ, cq = jj - g * ROWQ;
            int nb = g >> 6, ii = g & 63;
            int dr = which == 0 ? nb * 128 + (ii < 32 ? ii : ii + 32)
                                : nb * 128 + (ii < 32 ? ii + 32 : ii + 64);
            s = which ? su : sg; off = jj;
            di = (size_t)4 * SEG + (size_t)dr * ROWQ + cq;
        } else {                                  // W_down linear
            s = sd; off = i - 8 * SEG; di = i;
        }
        float4 v = s[off];
        u16x4 o = { f2bf(v.x), f2bf(v.y), f2bf(v.z), f2bf(v.w) };
        dst[di] = o;
    }
}

// ---------------- RMSNorm: fp32 in -> bf16 out ----------------
__global__ __launch_bounds__(256) void rmsnorm_kernel(const float* __restrict__ x,
                                                      const float* __restrict__ w,
                                                      u16* __restrict__ out) {
    const int row = blockIdx.x;
    const int tid = threadIdx.x;
    const float4* x4 = (const float4*)(x + (size_t)row * DD);
    float4 a = x4[tid * 2], b = x4[tid * 2 + 1];
    float s = a.x*a.x + a.y*a.y + a.z*a.z + a.w*a.w
            + b.x*b.x + b.y*b.y + b.z*b.z + b.w*b.w;
#pragma unroll
    for (int off = 32; off >= 1; off >>= 1) s += __shfl_xor(s, off, 64);
    __shared__ float red[4];
    if ((tid & 63) == 0) red[tid >> 6] = s;
    __syncthreads();
    float tot = red[0] + red[1] + red[2] + red[3];
    float rs = rsqrtf(tot * (1.f / DD) + 1e-6f);
    const float4* w4 = (const float4*)w;
    float4 wa = w4[tid * 2], wb = w4[tid * 2 + 1];
    u16x8 o = { f2bf(a.x*rs*wa.x), f2bf(a.y*rs*wa.y), f2bf(a.z*rs*wa.z), f2bf(a.w*rs*wa.w),
                f2bf(b.x*rs*wb.x), f2bf(b.y*rs*wb.y), f2bf(b.z*rs*wb.z), f2bf(b.w*rs*wb.w) };
    *(u16x8*)(out + (size_t)row * DD + tid * 8) = o;
}

// ============ 128x128 tile GEMM, BK=64, C = A(MxK) * B(NxK)^T ============
// Round-8 proven structure: 4 waves (2x2 of 64x64), single-buffered 32 KB LDS,
// __syncthreads ordering, XOR-swizzled rows via pre-swizzled gload SOURCE.
// EPI 1: outf = resid + c (fp32)
// EPI 3: fused GLU (32-row gate/up interleaved B): silu(g)*u, local pairing
// EPI 4: fused r/xp (32-row W_r/W_in interleaved B): sigmoid(r+bias0)*xp
// EPI 5: sigmoid(c + bias0) single output
template<int EPI>
__global__ __launch_bounds__(256)
void gemm_bt(const u16* __restrict__ A, const u16* __restrict__ Bw,
             int M, int N, int K,
             const float* __restrict__ bias0,
             const float* resid, float* outf,
             u16* __restrict__ out0, int Dsub) {
    __shared__ __align__(16) u16 lA[128 * 64];   // 16 KB
    __shared__ __align__(16) u16 lB[128 * 64];   // 16 KB
    const int tid  = threadIdx.x;
    const int lane = tid & 63;
    const int wave = tid >> 6;
    const int wr = (wave >> 1) << 6;
    const int wc = (wave & 1) << 6;
    const int brow = blockIdx.x * 128;
    const int bcol = blockIdx.y * 128;

    // staging: 32 rows/issue, 8 chunks/row; source chunk pre-swizzled
    const int srow  = tid >> 3;                    // 0..31
    const int schnk = (tid & 7) ^ (srow & 7);      // inverse-swizzle source
    const size_t soff = (size_t)srow * K + (schnk << 3);
    const u16* gA = A  + (size_t)brow * K + soff;
    const u16* gB = Bw + (size_t)bcol * K + soff;
    u16* lAp = lA + tid * 8;                       // linear dest, lane*16B
    u16* lBp = lB + tid * 8;

    // read-address pieces
    const int fr = lane & 15;
    const int lg = lane >> 4;                      // 0..3
    const int ck0 = ((lg)     ^ (fr & 7)) << 4;    // k-half 0 chunk byte
    const int ck1 = ((4 + lg) ^ (fr & 7)) << 4;    // k-half 1 chunk byte
    const char* lAc = (const char*)lA;
    const char* lBc = (const char*)lB;

    f32x4 acc[4][4];
#pragma unroll
    for (int i = 0; i < 4; ++i)
#pragma unroll
        for (int j = 0; j < 4; ++j)
            acc[i][j] = (f32x4){0.f, 0.f, 0.f, 0.f};

    for (int k0 = 0; k0 < K; k0 += 64) {
#pragma unroll
        for (int s = 0; s < 4; ++s) {
            gload16(gA + k0 + (size_t)s * 32 * K, lAp + s * 2048);
            gload16(gB + k0 + (size_t)s * 32 * K, lBp + s * 2048);
        }
        __syncthreads();
        s16x8 af[4][2], bq[4][2];
#pragma unroll
        for (int i = 0; i < 4; ++i) {
            const int ra = (wr + i * 16 + fr) * 128;
            const int rb = (wc + i * 16 + fr) * 128;
            af[i][0] = *(const s16x8*)(lAc + ra + ck0);
            af[i][1] = *(const s16x8*)(lAc + ra + ck1);
            bq[i][0] = *(const s16x8*)(lBc + rb + ck0);
            bq[i][1] = *(const s16x8*)(lBc + rb + ck1);
        }
#pragma unroll
        for (int h = 0; h < 2; ++h)
#pragma unroll
            for (int i = 0; i < 4; ++i)
#pragma unroll
                for (int j = 0; j < 4; ++j)
                    mfma16(acc[i][j], af[i][h], bq[j][h]);
        __syncthreads();
    }

    // MFMA-write -> VALU-read hazard fence
#pragma unroll
    for (int i = 0; i < 4; ++i)
#pragma unroll
        for (int j = 0; j < 4; ++j)
            asm volatile("s_nop 7" : "+v"(acc[i][j]));

    const int r0 = brow + wr + (lg << 2);

    if (EPI == 3 || EPI == 4) {
        // paired epilogue: first acc[i][0..1] pairs with second acc[i][2..3]
        const int nb = bcol >> 7;
        const int cbase = nb * 64 + (wc ? 32 : 0);
#pragma unroll
        for (int i = 0; i < 4; ++i)
#pragma unroll
            for (int j = 0; j < 2; ++j)
#pragma unroll
                for (int e = 0; e < 4; ++e) {
                    const int grow = r0 + i * 16 + e;
                    const int col  = cbase + j * 16 + fr;
                    const float g = acc[i][j][e];
                    const float u = acc[i][j + 2][e];
                    float v;
                    if (EPI == 3) v = g * sigm(g) * u;           // silu(gate)*up
                    else          v = sigm(g + bias0[col]) * u;  // sigmoid(r+br)*xp
                    out0[(size_t)grow * Dsub + col] = f2bf(v);
                }
        return;
    }

    const int c0 = bcol + wc + fr;
#pragma unroll
    for (int i = 0; i < 4; ++i) {
#pragma unroll
        for (int j = 0; j < 4; ++j) {
            const int gcol = c0 + j * 16;
#pragma unroll
            for (int e = 0; e < 4; ++e) {
                const int grow = r0 + i * 16 + e;
                float c = acc[i][j][e];
                if (EPI == 1) {
                    const size_t idx = (size_t)grow * N + gcol;
                    outf[idx] = resid[idx] + c;
                } else {  // EPI == 5
                    out0[(size_t)grow * Dsub + gcol] = f2bf(sigm(c + bias0[gcol]));
                }
            }
        }
    }
}

// ================= chunked RG-LRU scan (3 passes) =================
// BP = sigmoid(r+b_r)*xp precomputed by the EPI4 GEMM; b_t = sc * BP.
__global__ __launch_bounds__(256)
void scan_partial(const u16* __restrict__ BP,
                  const float* __restrict__ log_dec, float* __restrict__ carry) {
    const int d = blockIdx.x * 256 + threadIdx.x;
    const int k = blockIdx.y;
    const int b = blockIdx.z;
    float a = sigm(log_dec[d]);
    a = fminf(fmaxf(a, 1e-6f), 1.f - 1e-6f);
    const float sc = sqrtf(fmaxf(1.f - a * a, 0.f));
    float h = 0.f;
    size_t idx = ((size_t)b * TD + (size_t)k * CHL) * DD + d;
#pragma unroll 8
    for (int t = 0; t < CHL; ++t) {
        h = a * h + sc * bf2f(BP[idx]);
        idx += DD;
    }
    carry[((size_t)b * CHK + k) * DD + d] = h;
}

__global__ __launch_bounds__(256)
void scan_carry(const float* __restrict__ state, const float* __restrict__ log_dec,
                const float* __restrict__ carry, float* __restrict__ carryin,
                float* __restrict__ hfin) {
    const int d = blockIdx.x * 256 + threadIdx.x;
    const int b = blockIdx.y;
    float a = sigm(log_dec[d]);
    a = fminf(fmaxf(a, 1e-6f), 1.f - 1e-6f);
    float aL = a;
#pragma unroll
    for (int i = 0; i < 6; ++i) aL *= aL;   // a^64 == a^CHL
    float h = state[(size_t)b * DD + d];
#pragma unroll
    for (int k = 0; k < CHK; ++k) {
        const size_t ci = ((size_t)b * CHK + k) * DD + d;
        carryin[ci] = h;
        h = aL * h + carry[ci];
    }
    hfin[(size_t)b * DD + d] = h;
}

__global__ __launch_bounds__(256)
void scan_final(const u16* __restrict__ BP, const u16* __restrict__ G,
                const float* __restrict__ log_dec,
                const float* __restrict__ carryin, u16* __restrict__ HSG) {
    const int d = blockIdx.x * 256 + threadIdx.x;
    const int k = blockIdx.y;
    const int b = blockIdx.z;
    float a = sigm(log_dec[d]);
    a = fminf(fmaxf(a, 1e-6f), 1.f - 1e-6f);
    const float sc = sqrtf(fmaxf(1.f - a * a, 0.f));
    float h = carryin[((size_t)b * CHK + k) * DD + d];
    size_t idx = ((size_t)b * TD + (size_t)k * CHL) * DD + d;
#pragma unroll 8
    for (int t = 0; t < CHL; ++t) {
        h = a * h + sc * bf2f(BP[idx]);
        HSG[idx] = f2bf(h * bf2f(G[idx]));
        idx += DD;
    }
}

extern "C" void kernel_launch(void* const* d_in, const int* in_sizes, int n_in,
                              void* d_out, int out_size, void* d_ws, size_t ws_size,
                              hipStream_t stream) {
    const float* x       = (const float*)d_in[0];
    const float* state   = (const float*)d_in[1];
    const float* w_norm1 = (const float*)d_in[2];
    const float* W_in    = (const float*)d_in[3];
    const float* W_r     = (const float*)d_in[4];
    const float* b_r     = (const float*)d_in[5];
    const float* W_i     = (const float*)d_in[6];
    const float* b_i     = (const float*)d_in[7];
    const float* log_dec = (const float*)d_in[8];
    const float* W_out   = (const float*)d_in[9];
    const float* w_norm2 = (const float*)d_in[10];
    const float* W_gate  = (const float*)d_in[11];
    const float* W_up    = (const float*)d_in[12];
    const float* W_down  = (const float*)d_in[13];

    float* out  = (float*)d_out;
    float* hfin = out + (size_t)MD * DD;

    const size_t SEGU = (size_t)DD * DD;                    // u16 elems per D*D
    u16* w_rx    = (u16*)d_ws;                              // [W_r/W_in interleave] 2*SEG
    u16* w_i     = w_rx   + 2 * SEGU;                       // W_i
    u16* w_out   = w_rx   + 3 * SEGU;                       // W_out
    u16* w_gu    = w_rx   + 4 * SEGU;                       // [gate/up interleave] 4*SEG
    u16* w_down  = w_rx   + 8 * SEGU;                       // W_down 2*SEG
    u16* bufN    = w_rx   + 10 * SEGU;                      // M*D
    u16* bufBP   = bufN   + (size_t)MD * DD;                // M*D (bP; later act M*DI spans bufBP+bufG)
    u16* bufG    = bufBP  + (size_t)MD * DD;                // M*D
    u16* spare   = bufG   + (size_t)MD * DD;                // 2*M*D spare
    float* carry   = (float*)spare;                         // B*CHK*D fp32 (1 MB)
    float* carryin = carry + (size_t)BD * CHK * DD;         // B*CHK*D fp32 (1 MB)

    // 1) fused weight converts (r/in and gate/up 32-row interleaved)
    cvt_all<<<2048, 256, 0, stream>>>((const float4*)W_r, (const float4*)W_in,
                                      (const float4*)W_i, (const float4*)W_out,
                                      (const float4*)W_gate, (const float4*)W_up,
                                      (const float4*)W_down, (u16x4*)w_rx,
                                      (int)(10 * SEGU / 4));

    rmsnorm_kernel<<<MD, 256, 0, stream>>>(x, w_norm1, bufN);

    // bP = sigmoid(n@W_r^T + b_r) * (n@W_in^T) : stacked N=4096, fused pairing
    {
        dim3 g1(MD / 128, (2 * DD) / 128);
        gemm_bt<4><<<g1, 256, 0, stream>>>(bufN, w_rx, MD, 2 * DD, DD,
                                           b_r, nullptr, nullptr, bufBP, DD);
    }
    // g = sigmoid(n@W_i^T + b_i) : N=2048
    {
        dim3 g1b(MD / 128, DD / 128);
        gemm_bt<5><<<g1b, 256, 0, stream>>>(bufN, w_i, MD, DD, DD,
                                            b_i, nullptr, nullptr, bufG, DD);
    }

    // chunked RG-LRU scan
    {
        dim3 gp(DD / 256, CHK, BD);
        scan_partial<<<gp, 256, 0, stream>>>(bufBP, log_dec, carry);
        dim3 gc(DD / 256, BD);
        scan_carry<<<gc, 256, 0, stream>>>(state, log_dec, carry, carryin, hfin);
        scan_final<<<gp, 256, 0, stream>>>(bufBP, bufG, log_dec, carryin, bufN);
    }

    // x2 = x + hsg @ W_out^T
    {
        dim3 g2(MD / 128, DD / 128);
        gemm_bt<1><<<g2, 256, 0, stream>>>(bufN, w_out, MD, DD, DD,
                                           nullptr, x, out, nullptr, 0);
    }

    rmsnorm_kernel<<<MD, 256, 0, stream>>>(out, w_norm2, bufN);

    // fused gate/up + GLU: stacked N=8192, writes act (M x DI) directly
    {
        dim3 g3(MD / 128, (2 * DID) / 128);
        gemm_bt<3><<<g3, 256, 0, stream>>>(bufN, w_gu, MD, 2 * DID, DD,
                                           nullptr, nullptr, nullptr, bufBP, DID);
    }

    // out = x2 + act @ W_down^T
    {
        dim3 g4(MD / 128, DD / 128);
        gemm_bt<1><<<g4, 256, 0, stream>>>(bufBP, w_down, MD, DD, DID,
                                           nullptr, out, out, nullptr, 0);
    }
}